// Round 5
// baseline (142.073 us; speedup 1.0000x reference)
//
#include <hip/hip_runtime.h>
#include <hip/hip_bf16.h>
#include <stdint.h>

typedef short bf16x8 __attribute__((ext_vector_type(8)));
typedef float f32x4  __attribute__((ext_vector_type(4)));

#define B_    32
#define CIN   32
#define COUT  64
#define H_    128
#define W_    128
#define HW    (H_ * W_)
#define PXW   130
#define SLOTS 6            // rolling ring of padded rows
#define ROWS_PER_BLK 8
#define TILES 4            // ROWS_PER_BLK / 2
#define NBLK  512          // 32 images * 16 row-groups

static __device__ __forceinline__ ushort f2bf(float v) {
    __hip_bfloat16 h = __float2bfloat16(v);
    return __builtin_bit_cast(ushort, h);
}

// ---------------------------------------------------------------------------
// Weight pack: [Cout][Cin][3][3] fp32 -> bf16 A-fragment order
// Wp[tap][ocg][lane][j] = W[ocg*16 + (lane&15)][8*(lane>>4)+j][ky][kx]
// ---------------------------------------------------------------------------
__global__ void prep_w_kernel(const float* __restrict__ wt, ushort* __restrict__ Wp) {
    int p = blockIdx.x * blockDim.x + threadIdx.x;
    if (p >= COUT * CIN * 9) return;  // 18432
    int j    = p & 7;
    int lane = (p >> 3) & 63;
    int g    = (p >> 9) & 3;
    int tap  = p >> 11;
    int oc   = g * 16 + (lane & 15);
    int cin  = (lane >> 4) * 8 + j;
    int ky   = tap / 3;
    int kx   = tap % 3;
    Wp[p] = f2bf(wt[(((size_t)oc * CIN + cin) * 3 + ky) * 3 + kx]);
}

// ---------------------------------------------------------------------------
// Pipelined fused conv. Block = (b, 8 output rows) = 4 tiles of 2 rows.
// LDS = 6-row ring of padded rows (slot = p % 6), bf16 NHWC, XOR-swizzled.
// Per tile: issue next rows' loads -> MFMA from ring -> cvt+ds_write -> store
// -> one barrier. Pad columns (px=0,129) zero-filled once in prologue.
// ---------------------------------------------------------------------------
__global__ __launch_bounds__(256, 2) void conv_pipe_kernel(
    const float* __restrict__ in, const ushort* __restrict__ Wp,
    float* __restrict__ out) {
    __shared__ ushort lds[SLOTS * PXW * 32];   // 49,920 B

    int hw_blk  = blockIdx.x;
    int logical = (hw_blk & 7) * (NBLK / 8) + (hw_blk >> 3);   // bijective, 512%8==0
    int b   = logical >> 4;                 // /16
    int bh0 = (logical & 15) * ROWS_PER_BLK;
    int tid = threadIdx.x;

    const float* ib = in + (size_t)b * CIN * HW;

    // ---- prologue: zero the pad columns (px=0 and 129, all 6 slots) ----
    if (tid < 2 * SLOTS) {
        int s  = tid >> 1;
        int px = (tid & 1) ? (PXW - 1) : 0;
        char* base = (char*)lds + (uint32_t)(s * PXW + px) * 64u;
        bf16x8 z = (bf16x8)0;
#pragma unroll
        for (int q = 0; q < 4; ++q) *(bf16x8*)(base + q * 16) = z;
    }

    // ---- prologue: stage padded rows bh0..bh0+3, interior px (2 cols/thread)
#pragma unroll
    for (int c0 = 0; c0 < 2; ++c0) {
        int c  = c0 * 256 + tid;          // 0..511
        int rr = c >> 7;                  // 0..3
        int px = 1 + (c & 127);
        int p  = bh0 + rr;
        int gy = p - 1;
        float v[32];
        if (gy >= 0 && gy < H_) {
            const float* src = ib + (size_t)gy * W_ + (px - 1);
#pragma unroll
            for (int ch = 0; ch < 32; ++ch) v[ch] = src[(size_t)ch * HW];
        } else {
#pragma unroll
            for (int ch = 0; ch < 32; ++ch) v[ch] = 0.f;
        }
        int slot = p % SLOTS;
        uint32_t base = (uint32_t)(slot * PXW + px) * 64u;
        uint32_t sw = (((uint32_t)px >> 1) & 3u) << 4;
#pragma unroll
        for (int q = 0; q < 4; ++q) {
            bf16x8 w;
#pragma unroll
            for (int j = 0; j < 8; ++j) w[j] = (short)f2bf(v[q * 8 + j]);
            *(bf16x8*)((char*)lds + base + (((uint32_t)q << 4) ^ sw)) = w;
        }
    }
    __syncthreads();

    int wid  = tid >> 6;
    int lane = tid & 63;
    int llo  = lane & 15;
    int lhi  = lane >> 4;
    int row  = wid >> 1;              // 0..1 (output row within tile)
    int px0  = (wid & 1) * 64;        // px half

    int st_rr = tid >> 7;             // staging: 2 rows x 128 px = 256 cols
    int st_px = 1 + (tid & 127);

    for (int t = 0; t < TILES; ++t) {
        int h0t = bh0 + 2 * t;

        // ---- A: issue next tile's stage loads (unconditional address) ----
        int  sp   = h0t + 4 + st_rr;            // padded row to stage
        int  sgy  = sp - 1;
        bool zero = (sgy >= H_);
        int  gy_e = zero ? 0 : sgy;
        const float* src = ib + (size_t)gy_e * W_ + (st_px - 1);
        float stv[32];
#pragma unroll
        for (int ch = 0; ch < 32; ++ch) stv[ch] = src[(size_t)ch * HW];

        // ---- B: compute tile t from the ring ----
        f32x4 acc[4][4];
#pragma unroll
        for (int g = 0; g < 4; ++g)
#pragma unroll
            for (int nf = 0; nf < 4; ++nf) {
                acc[g][nf][0] = 0.f; acc[g][nf][1] = 0.f;
                acc[g][nf][2] = 0.f; acc[g][nf][3] = 0.f;
            }

#pragma unroll
        for (int tap = 0; tap < 9; ++tap) {
            int dy = tap / 3;
            int dx = tap % 3;
            int p  = h0t + row + dy;
            int rbase = (p % SLOTS) * PXW;
            bf16x8 Af[4];
#pragma unroll
            for (int g = 0; g < 4; ++g)
                Af[g] = *(const bf16x8*)(Wp + ((size_t)(tap * 4 + g) * 64 + lane) * 8);
#pragma unroll
            for (int nf = 0; nf < 4; ++nf) {
                int px = px0 + nf * 16 + llo + dx;
                uint32_t byte = (uint32_t)(rbase + px) * 64u +
                                (((uint32_t)lhi << 4) ^ ((((uint32_t)px >> 1) & 3u) << 4));
                bf16x8 Bf = *(const bf16x8*)((const char*)lds + byte);
#pragma unroll
                for (int g = 0; g < 4; ++g)
                    acc[g][nf] = __builtin_amdgcn_mfma_f32_16x16x32_bf16(Af[g], Bf, acc[g][nf], 0, 0, 0);
            }
        }

        // ---- C: cvt + ds_write staged rows (waits on stage loads only) ----
        if (t < TILES - 1) {
            int slot = sp % SLOTS;
            uint32_t base = (uint32_t)(slot * PXW + st_px) * 64u;
            uint32_t sw = (((uint32_t)st_px >> 1) & 3u) << 4;
#pragma unroll
            for (int q = 0; q < 4; ++q) {
                bf16x8 w;
#pragma unroll
                for (int j = 0; j < 8; ++j)
                    w[j] = zero ? (short)0 : (short)f2bf(stv[q * 8 + j]);
                *(bf16x8*)((char*)lds + base + (((uint32_t)q << 4) ^ sw)) = w;
            }
        }

        // ---- D: store tile t (plain stores, drain across next tile) ----
        int h = h0t + row;
        float* obase = out + (size_t)b * COUT * HW + (size_t)h * W_;
#pragma unroll
        for (int g = 0; g < 4; ++g)
#pragma unroll
            for (int nf = 0; nf < 4; ++nf) {
                int x = px0 + nf * 16 + llo;
#pragma unroll
                for (int r = 0; r < 4; ++r) {
                    int oc = g * 16 + lhi * 4 + r;
                    obase[(size_t)oc * HW + x] = acc[g][nf][r];
                }
            }

        __syncthreads();
    }
}

// ---------------------------------------------------------------------------
// Fallback: naive fp32 direct conv (only if workspace is too small for Wp)
// ---------------------------------------------------------------------------
__global__ void conv_naive_kernel(const float* __restrict__ in,
                                  const float* __restrict__ wt,
                                  float* __restrict__ out) {
    int idx = blockIdx.x * blockDim.x + threadIdx.x;
    if (idx >= B_ * COUT * HW) return;
    int w  = idx & 127;
    int h  = (idx >> 7) & 127;
    int oc = (idx >> 14) & 63;
    int b  = idx >> 20;
    float s = 0.f;
    for (int c = 0; c < CIN; ++c)
        for (int ky = 0; ky < 3; ++ky) {
            int y = h + ky - 1;
            if ((unsigned)y >= (unsigned)H_) continue;
            for (int kx = 0; kx < 3; ++kx) {
                int x = w + kx - 1;
                if ((unsigned)x >= (unsigned)W_) continue;
                s += in[((size_t)(b * CIN + c) * H_ + y) * W_ + x] *
                     wt[(((size_t)oc * CIN + c) * 3 + ky) * 3 + kx];
            }
        }
    out[idx] = s;
}

extern "C" void kernel_launch(void* const* d_in, const int* in_sizes, int n_in,
                              void* d_out, int out_size, void* d_ws, size_t ws_size,
                              hipStream_t stream) {
    const float* in = (const float*)d_in[0];
    const float* wt = (const float*)d_in[1];
    float* out = (float*)d_out;

    size_t Wp_bytes = (size_t)COUT * CIN * 9 * 2;   // 36,864

    if (ws_size >= Wp_bytes) {
        ushort* Wp = (ushort*)d_ws;
        prep_w_kernel<<<(COUT * CIN * 9 + 255) / 256, 256, 0, stream>>>(wt, Wp);
        conv_pipe_kernel<<<NBLK, 256, 0, stream>>>(in, Wp, out);
    } else {
        int total = B_ * COUT * HW;
        conv_naive_kernel<<<(total + 255) / 256, 256, 0, stream>>>(in, wt, out);
    }
}

// Round 6
// 48.553 us; speedup vs baseline: 2.9262x; 2.9262x over previous
//
#include <hip/hip_runtime.h>
#include <hip/hip_bf16.h>
#include <stdint.h>

typedef short bf16x8 __attribute__((ext_vector_type(8)));
typedef float f32x4  __attribute__((ext_vector_type(4)));

#define B_   32
#define CIN  32
#define COUT 64
#define H_   128
#define W_   128
#define HW   (H_ * W_)
#define T_   2            // output rows per block
#define RROWS 4           // staged input rows = T_+2
#define PXW  130          // padded width
#define SCW  68           // scratch row stride in words (16B-aligned, bank-friendly)

static __device__ __forceinline__ ushort f2bf(float v) {
    __hip_bfloat16 h = __float2bfloat16(v);
    return __builtin_bit_cast(ushort, h);
}

// ---------------------------------------------------------------------------
// Weight pack: [Cout][Cin][3][3] fp32 -> bf16 A-fragment order
// Wp[tap][ocg][lane][j] = W[ocg*16 + (lane&15)][8*(lane>>4)+j][ky][kx]
// ---------------------------------------------------------------------------
__global__ void prep_w_kernel(const float* __restrict__ wt, ushort* __restrict__ Wp) {
    int p = blockIdx.x * blockDim.x + threadIdx.x;
    if (p >= COUT * CIN * 9) return;  // 18432
    int j    = p & 7;
    int lane = (p >> 3) & 63;
    int g    = (p >> 9) & 3;
    int tap  = p >> 11;
    int oc   = g * 16 + (lane & 15);
    int cin  = (lane >> 4) * 8 + j;
    int ky   = tap / 3;
    int kx   = tap % 3;
    Wp[p] = f2bf(wt[(((size_t)oc * CIN + cin) * 3 + ky) * 3 + kx]);
}

// ---------------------------------------------------------------------------
// Fused conv: stage 4 padded rows (NCHW fp32 -> bf16 NHWC in LDS, swizzled),
// implicit-GEMM, then a full-line epilogue: acc -> per-wave LDS scratch ->
// f32x4 row reads -> global_store_dwordx4 (256B contiguous per 16 lanes).
// Avoids L2 write-allocate RFO (R5 showed FETCH += output size with 64B
// partial-line stores). Block = (b, 2 rows); 4 waves = 2 rows x 2 px-halves.
// ---------------------------------------------------------------------------
__global__ __launch_bounds__(256, 3) void conv_fused_kernel(
    const float* __restrict__ in, const ushort* __restrict__ Wp,
    float* __restrict__ out) {
    __shared__ ushort lds[RROWS * PXW * 32];     // 33,280 B
    __shared__ float  scr[4][16 * SCW];          // 17,408 B (per-wave scratch)

    int hw_blk  = blockIdx.x;
    int logical = (hw_blk & 7) * 256 + (hw_blk >> 3);   // grid = 2048 = 8*256
    int b   = logical >> 6;          // /64
    int h0  = (logical & 63) * T_;
    int tid = threadIdx.x;

    // ---- stage: thread = one (row, px) column, loop 32 channels ----
    for (int i = tid; i < RROWS * PXW; i += 256) {
        int r  = i / PXW;
        int px = i - r * PXW;
        int gy = h0 + r - 1;
        bf16x8 v[4];
        if (gy >= 0 && gy < H_ && px >= 1 && px <= W_) {
            const float* src = in + ((size_t)b * CIN * H_ + gy) * W_ + (px - 1);
#pragma unroll
            for (int q = 0; q < 4; ++q)
#pragma unroll
                for (int j = 0; j < 8; ++j)
                    v[q][j] = (short)f2bf(src[(size_t)(q * 8 + j) * HW]);
        } else {
#pragma unroll
            for (int q = 0; q < 4; ++q)
#pragma unroll
                for (int j = 0; j < 8; ++j)
                    v[q][j] = 0;
        }
        uint32_t base_byte = (uint32_t)i * 64;
        uint32_t sw = ((uint32_t)(px >> 1) & 3u) << 4;
#pragma unroll
        for (int q = 0; q < 4; ++q)
            *(bf16x8*)((char*)lds + base_byte + (((uint32_t)q << 4) ^ sw)) = v[q];
    }
    __syncthreads();

    // ---- compute: wave = (row = wid>>1, px half = wid&1), 64 oc x 64 px ----
    int wid  = tid >> 6;
    int lane = tid & 63;
    int llo  = lane & 15;
    int lhi  = lane >> 4;
    int row  = wid >> 1;            // 0..1
    int px0  = (wid & 1) * 64;
    int h    = h0 + row;

    f32x4 acc[4][4];
#pragma unroll
    for (int g = 0; g < 4; ++g)
#pragma unroll
        for (int nf = 0; nf < 4; ++nf) {
            acc[g][nf][0] = 0.f; acc[g][nf][1] = 0.f;
            acc[g][nf][2] = 0.f; acc[g][nf][3] = 0.f;
        }

#pragma unroll
    for (int tap = 0; tap < 9; ++tap) {
        int dy = tap / 3;
        int dx = tap % 3;
        int rbase = (row + dy) * PXW;
#pragma unroll
        for (int nf = 0; nf < 4; ++nf) {
            int px = px0 + nf * 16 + llo + dx;
            uint32_t byte = (uint32_t)(rbase + px) * 64u +
                            (((uint32_t)lhi << 4) ^ ((((uint32_t)px >> 1) & 3u) << 4));
            bf16x8 Bf = *(const bf16x8*)((const char*)lds + byte);
#pragma unroll
            for (int g = 0; g < 4; ++g) {
                bf16x8 Af = *(const bf16x8*)(Wp + ((size_t)(tap * 4 + g) * 64 + lane) * 8);
                acc[g][nf] = __builtin_amdgcn_mfma_f32_16x16x32_bf16(Af, Bf, acc[g][nf], 0, 0, 0);
            }
        }
    }

    // ---- epilogue: per-wave LDS transpose -> full-line dwordx4 stores ----
    // C/D frag: value acc[g][nf][r] is (oc' = lhi*4+r, px' = nf*16+llo).
    // Scratch row oc' (stride 68 words); readback lane: oc'=j*4+lhi,
    // px'=llo*4 -> f32x4; store 256B contiguous per 16 lanes (full lines).
    float* myscr = &scr[wid][0];
    float* obase = out + (size_t)b * COUT * HW + (size_t)h * W_ + px0;
#pragma unroll
    for (int g = 0; g < 4; ++g) {
#pragma unroll
        for (int nf = 0; nf < 4; ++nf)
#pragma unroll
            for (int r = 0; r < 4; ++r)
                myscr[(lhi * 4 + r) * SCW + nf * 16 + llo] = acc[g][nf][r];
        __builtin_amdgcn_s_waitcnt(0);   // lgkmcnt(0): scratch writes visible
#pragma unroll
        for (int j = 0; j < 4; ++j) {
            int ocp = j * 4 + lhi;       // 0..15
            f32x4 vv = *(const f32x4*)(myscr + ocp * SCW + llo * 4);
            int oc = g * 16 + ocp;
            *(f32x4*)(obase + (size_t)oc * HW + llo * 4) = vv;
        }
        __builtin_amdgcn_s_waitcnt(0);   // drain reads before overwriting scratch
    }
}

// ---------------------------------------------------------------------------
// Fallback: naive fp32 direct conv (only if workspace is too small for Wp)
// ---------------------------------------------------------------------------
__global__ void conv_naive_kernel(const float* __restrict__ in,
                                  const float* __restrict__ wt,
                                  float* __restrict__ out) {
    int idx = blockIdx.x * blockDim.x + threadIdx.x;
    if (idx >= B_ * COUT * HW) return;
    int w  = idx & 127;
    int h  = (idx >> 7) & 127;
    int oc = (idx >> 14) & 63;
    int b  = idx >> 20;
    float s = 0.f;
    for (int c = 0; c < CIN; ++c)
        for (int ky = 0; ky < 3; ++ky) {
            int y = h + ky - 1;
            if ((unsigned)y >= (unsigned)H_) continue;
            for (int kx = 0; kx < 3; ++kx) {
                int x = w + kx - 1;
                if ((unsigned)x >= (unsigned)W_) continue;
                s += in[((size_t)(b * CIN + c) * H_ + y) * W_ + x] *
                     wt[(((size_t)oc * CIN + c) * 3 + ky) * 3 + kx];
            }
        }
    out[idx] = s;
}

extern "C" void kernel_launch(void* const* d_in, const int* in_sizes, int n_in,
                              void* d_out, int out_size, void* d_ws, size_t ws_size,
                              hipStream_t stream) {
    const float* in = (const float*)d_in[0];
    const float* wt = (const float*)d_in[1];
    float* out = (float*)d_out;

    size_t Wp_bytes = (size_t)COUT * CIN * 9 * 2;   // 36,864

    if (ws_size >= Wp_bytes) {
        ushort* Wp = (ushort*)d_ws;
        prep_w_kernel<<<(COUT * CIN * 9 + 255) / 256, 256, 0, stream>>>(wt, Wp);
        conv_fused_kernel<<<B_ * (H_ / T_), 256, 0, stream>>>(in, Wp, out);
    } else {
        int total = B_ * COUT * HW;
        conv_naive_kernel<<<(total + 255) / 256, 256, 0, stream>>>(in, wt, out);
    }
}